// Round 2
// baseline (150.537 us; speedup 1.0000x reference)
//
#include <hip/hip_runtime.h>
#include <hip/hip_bf16.h>

// AVWGCN: per-node graph conv. N=10000 nodes, C=HID=64, B=32, K=2.
// One 256-thread block (4 waves) per node.
// Round 2: hoist ALL global loads (emb, x, W0, W1) to the top of the kernel,
// before any barrier, so each block's full 64 KB demand is in flight at once.
//   Phase A: softmax(relu(E[n])) row-wise -> St (transposed, fp32, LDS)
//   Phase B: XG1 = X @ S via MFMA -> LDS
//   Phase C: OUT = X@W0 + XG1@W1 + bias via MFMA (W from hoisted registers)

constexpr int N_ = 10000;
constexpr int C_ = 64;
constexpr int H_ = 64;
constexpr int B_ = 32;
constexpr int STP = 67;   // odd LDS stride (fp32 elems): <=2-way bank conflicts

typedef __bf16 bf16x8 __attribute__((ext_vector_type(8)));
typedef float  f32x4  __attribute__((ext_vector_type(4)));

__global__ __launch_bounds__(256, 4) void avwgcn_kernel(
    const float* __restrict__ x,      // (B, N, C)
    const float* __restrict__ emb,    // (N, C, C)
    const float* __restrict__ wpool,  // (K, N, C, H)
    const float* __restrict__ bias,   // (N, H)
    float* __restrict__ out)          // (B, N, H)
{
    __shared__ float st[64 * STP];    // st[m][c] = S[c][m]  (S = softmax(relu(E)))
    __shared__ float g1[32 * STP];    // g1[b][m] = XG1[b][m]

    const int n = blockIdx.x;
    const int t = threadIdx.x;
    const int w = t >> 6;     // wave 0..3 -> owns output cols w*16..w*16+15
    const int l = t & 63;
    const int r = l & 15;     // frag row/col within tile
    const int g = l >> 4;     // k-group 0..3

    // =============== issue ALL global loads up front (use-order) ===============
    // emb (needed first, by softmax)
    const int c = t >> 2;     // row of E (0..63)
    const int q = t & 3;      // 16-wide column segment
    float4 ef[4];
    {
        const float* ep = emb + (size_t)n * (C_ * C_) + c * C_ + q * 16;
        #pragma unroll
        for (int i = 0; i < 4; ++i)
            ef[i] = *reinterpret_cast<const float4*>(ep + i * 4);
    }

    // x (needed by phase B)
    float4 xf[2][2][2];
    #pragma unroll
    for (int mt = 0; mt < 2; ++mt) {
        #pragma unroll
        for (int kt = 0; kt < 2; ++kt) {
            const float* xp = x + (size_t)(mt * 16 + r) * (N_ * C_)
                                + (size_t)n * C_ + kt * 32 + g * 8;
            xf[mt][kt][0] = *reinterpret_cast<const float4*>(xp);
            xf[mt][kt][1] = *reinterpret_cast<const float4*>(xp + 4);
        }
    }

    // W0, W1 (needed last, by phase C) — 32 scalar dwords held in registers
    float wv[2][2][8];
    {
        const float* wbase = wpool + (size_t)n * (C_ * H_);
        #pragma unroll
        for (int mat = 0; mat < 2; ++mat) {
            const float* wm = wbase + (size_t)mat * N_ * (C_ * H_);
            #pragma unroll
            for (int kt = 0; kt < 2; ++kt) {
                const float* wp = wm + (size_t)(kt * 32 + g * 8) * H_ + w * 16 + r;
                #pragma unroll
                for (int i = 0; i < 8; ++i)
                    wv[mat][kt][i] = wp[i * H_];
            }
        }
    }

    const float bv = bias[(size_t)n * H_ + w * 16 + r];

    // ---------------- Phase A: row-wise softmax(relu(E[n])) ----------------
    {
        float v[16];
        #pragma unroll
        for (int i = 0; i < 4; ++i) {
            v[i * 4 + 0] = ef[i].x; v[i * 4 + 1] = ef[i].y;
            v[i * 4 + 2] = ef[i].z; v[i * 4 + 3] = ef[i].w;
        }
        float s = 0.f;
        #pragma unroll
        for (int i = 0; i < 16; ++i) {
            float e = __expf(fmaxf(v[i], 0.f));
            v[i] = e;
            s += e;
        }
        // quad (lanes t^1, t^2) holds the other 48 columns of this row
        s += __shfl_xor(s, 1);
        s += __shfl_xor(s, 2);
        const float inv = 1.0f / s;
        #pragma unroll
        for (int i = 0; i < 16; ++i)
            st[(q * 16 + i) * STP + c] = v[i] * inv;   // transposed store
    }

    // X A-frags: A[row=r][k=(g*8+i)+kt*32], row = mt*16+r is the batch index.
    bf16x8 xa[2][2];
    #pragma unroll
    for (int mt = 0; mt < 2; ++mt) {
        #pragma unroll
        for (int kt = 0; kt < 2; ++kt) {
            bf16x8 f;
            f[0] = (__bf16)xf[mt][kt][0].x; f[1] = (__bf16)xf[mt][kt][0].y;
            f[2] = (__bf16)xf[mt][kt][0].z; f[3] = (__bf16)xf[mt][kt][0].w;
            f[4] = (__bf16)xf[mt][kt][1].x; f[5] = (__bf16)xf[mt][kt][1].y;
            f[6] = (__bf16)xf[mt][kt][1].z; f[7] = (__bf16)xf[mt][kt][1].w;
            xa[mt][kt] = f;
        }
    }

    __syncthreads();

    // ---------------- Phase B: XG1 = X @ S ----------------
    f32x4 accg[2];
    accg[0] = (f32x4){0.f, 0.f, 0.f, 0.f};
    accg[1] = (f32x4){0.f, 0.f, 0.f, 0.f};
    #pragma unroll
    for (int kt = 0; kt < 2; ++kt) {
        // B-frag: S[k=c][col=m], col = w*16+r, k = kt*32+g*8+i -> st rows
        const float* sp = st + (w * 16 + r) * STP + kt * 32 + g * 8;
        bf16x8 sb;
        #pragma unroll
        for (int i = 0; i < 8; ++i) sb[i] = (__bf16)sp[i];
        #pragma unroll
        for (int mt = 0; mt < 2; ++mt)
            accg[mt] = __builtin_amdgcn_mfma_f32_16x16x32_bf16(
                xa[mt][kt], sb, accg[mt], 0, 0, 0);
    }

    // C/D layout: col = lane&15, row = g*4 + reg -> scatter into g1[b][m]
    #pragma unroll
    for (int mt = 0; mt < 2; ++mt)
        #pragma unroll
        for (int ri = 0; ri < 4; ++ri)
            g1[(mt * 16 + g * 4 + ri) * STP + (w * 16 + r)] = accg[mt][ri];

    __syncthreads();

    // ---------------- Phase C: OUT = X@W0 + XG1@W1 + bias ----------------
    // XG1 A-frags from LDS
    bf16x8 ga[2][2];
    #pragma unroll
    for (int mt = 0; mt < 2; ++mt) {
        #pragma unroll
        for (int kt = 0; kt < 2; ++kt) {
            const float* gp = g1 + (mt * 16 + r) * STP + kt * 32 + g * 8;
            bf16x8 f;
            #pragma unroll
            for (int i = 0; i < 8; ++i) f[i] = (__bf16)gp[i];
            ga[mt][kt] = f;
        }
    }

    f32x4 acc[2];
    acc[0] = (f32x4){0.f, 0.f, 0.f, 0.f};
    acc[1] = (f32x4){0.f, 0.f, 0.f, 0.f};

    #pragma unroll
    for (int kt = 0; kt < 2; ++kt) {
        bf16x8 wb;
        #pragma unroll
        for (int i = 0; i < 8; ++i) wb[i] = (__bf16)wv[0][kt][i];
        #pragma unroll
        for (int mt = 0; mt < 2; ++mt)
            acc[mt] = __builtin_amdgcn_mfma_f32_16x16x32_bf16(
                xa[mt][kt], wb, acc[mt], 0, 0, 0);
    }
    #pragma unroll
    for (int kt = 0; kt < 2; ++kt) {
        bf16x8 wb;
        #pragma unroll
        for (int i = 0; i < 8; ++i) wb[i] = (__bf16)wv[1][kt][i];
        #pragma unroll
        for (int mt = 0; mt < 2; ++mt)
            acc[mt] = __builtin_amdgcn_mfma_f32_16x16x32_bf16(
                ga[mt][kt], wb, acc[mt], 0, 0, 0);
    }

    // Epilogue: add per-node bias, store.
    #pragma unroll
    for (int mt = 0; mt < 2; ++mt) {
        #pragma unroll
        for (int ri = 0; ri < 4; ++ri) {
            const int b = mt * 16 + g * 4 + ri;
            const int o = w * 16 + r;
            out[(size_t)b * (N_ * H_) + (size_t)n * H_ + o] = acc[mt][ri] + bv;
        }
    }
}

extern "C" void kernel_launch(void* const* d_in, const int* in_sizes, int n_in,
                              void* d_out, int out_size, void* d_ws, size_t ws_size,
                              hipStream_t stream) {
    const float* x    = (const float*)d_in[0];
    const float* emb  = (const float*)d_in[1];
    const float* wp   = (const float*)d_in[2];
    const float* bias = (const float*)d_in[3];
    float* out = (float*)d_out;
    avwgcn_kernel<<<N_, 256, 0, stream>>>(x, emb, wp, bias, out);
}

// Round 3
// 147.930 us; speedup vs baseline: 1.0176x; 1.0176x over previous
//
#include <hip/hip_runtime.h>
#include <hip/hip_bf16.h>

// AVWGCN: N=10000 nodes, C=HID=64, B=32, K=2.
// Round 3: ZERO-BARRIER design. One wave per node (4 indep waves / 256-thr block).
//   Lane l owns row l of E  -> softmax(relu) is lane-local (no shuffles).
//   Algebra: OUT = X@W0 + X@M1 + bias, M1 = diag(1/rowsum) * (exp(relu(E)) @ W1).
//   All LDS wave-private; cross-lane handoff via in-order DS + lgkmcnt fences.
//   W0/W1 global frag loads software-pipelined across col-tiles.

constexpr int N_ = 10000;
constexpr int C_ = 64;
constexpr int H_ = 64;
constexpr int STR = 72;   // bf16 elems per LDS row (144 B): 16B-aligned rows, spread banks

typedef __bf16 bf16x8 __attribute__((ext_vector_type(8)));
typedef float  f32x4  __attribute__((ext_vector_type(4)));

static __device__ __forceinline__ ushort f2b(float v) {
    __bf16 b = (__bf16)v;
    return __builtin_bit_cast(ushort, b);
}

// Wave-local LDS fence: order prior ds ops before later ones, wait completion.
static __device__ __forceinline__ void wave_lds_fence() {
    __builtin_amdgcn_sched_barrier(0);
    asm volatile("s_waitcnt lgkmcnt(0)" ::: "memory");
    __builtin_amdgcn_sched_barrier(0);
}

// ---- Phase B step: M1 col-tile CT (16 cols of o), W1 frags pipelined ----
template<int CT, bool PRE>
static __device__ __forceinline__ void m_step(
    const float* __restrict__ w1, ushort* st,
    const bf16x8 (&af)[4][2], const float4 (&invc)[4],
    float (&wcur)[2][8], float (&wnxt)[2][8], int r, int g)
{
    if (PRE) {
        #pragma unroll
        for (int kt = 0; kt < 2; ++kt)
            #pragma unroll
            for (int i = 0; i < 8; ++i)
                wnxt[kt][i] = w1[(kt * 32 + g * 8 + i) * H_ + (CT + 1) * 16 + r];
    }
    f32x4 macc[4];
    #pragma unroll
    for (int rt = 0; rt < 4; ++rt) macc[rt] = (f32x4){0.f, 0.f, 0.f, 0.f};
    #pragma unroll
    for (int kt = 0; kt < 2; ++kt) {
        bf16x8 wb;
        #pragma unroll
        for (int i = 0; i < 8; ++i) wb[i] = (__bf16)wcur[kt][i];
        #pragma unroll
        for (int rt = 0; rt < 4; ++rt)
            macc[rt] = __builtin_amdgcn_mfma_f32_16x16x32_bf16(
                af[rt][kt], wb, macc[rt], 0, 0, 0);
    }
    // scale rows by inv[c], pack bf16, write transposed: m[o][c], o=CT*16+r
    #pragma unroll
    for (int rt = 0; rt < 4; ++rt) {
        ushort b0 = f2b(macc[rt][0] * invc[rt].x);
        ushort b1 = f2b(macc[rt][1] * invc[rt].y);
        ushort b2 = f2b(macc[rt][2] * invc[rt].z);
        ushort b3 = f2b(macc[rt][3] * invc[rt].w);
        uint2 pk;
        pk.x = (uint)b0 | ((uint)b1 << 16);
        pk.y = (uint)b2 | ((uint)b3 << 16);
        *(uint2*)(st + (CT * 16 + r) * STR + rt * 16 + g * 4) = pk;
    }
}

// ---- Phase C step: OUT col-tile CT, W0 frags pipelined ----
template<int CT, bool PRE>
static __device__ __forceinline__ void c_step(
    const float* __restrict__ w0, const ushort* st,
    const bf16x8 (&xa)[2][2], float bv,
    float (&wcur)[2][8], float (&wnxt)[2][8],
    float* __restrict__ outp, int r, int g)
{
    if (PRE) {
        #pragma unroll
        for (int kt = 0; kt < 2; ++kt)
            #pragma unroll
            for (int i = 0; i < 8; ++i)
                wnxt[kt][i] = w0[(kt * 32 + g * 8 + i) * H_ + (CT + 1) * 16 + r];
    }
    bf16x8 mb[2];
    #pragma unroll
    for (int kt = 0; kt < 2; ++kt)
        mb[kt] = *(const bf16x8*)(st + (CT * 16 + r) * STR + kt * 32 + g * 8);

    f32x4 acc[2];
    #pragma unroll
    for (int mt = 0; mt < 2; ++mt) acc[mt] = (f32x4){bv, bv, bv, bv};

    #pragma unroll
    for (int kt = 0; kt < 2; ++kt) {
        bf16x8 wb;
        #pragma unroll
        for (int i = 0; i < 8; ++i) wb[i] = (__bf16)wcur[kt][i];
        #pragma unroll
        for (int mt = 0; mt < 2; ++mt) {
            acc[mt] = __builtin_amdgcn_mfma_f32_16x16x32_bf16(
                xa[mt][kt], wb, acc[mt], 0, 0, 0);
            acc[mt] = __builtin_amdgcn_mfma_f32_16x16x32_bf16(
                xa[mt][kt], mb[kt], acc[mt], 0, 0, 0);
        }
    }
    #pragma unroll
    for (int mt = 0; mt < 2; ++mt)
        #pragma unroll
        for (int ri = 0; ri < 4; ++ri)
            outp[(size_t)(mt * 16 + g * 4 + ri) * (N_ * H_) + CT * 16] = acc[mt][ri];
}

__global__ __launch_bounds__(256, 4) void avwgcn_kernel(
    const float* __restrict__ x,      // (B, N, C)
    const float* __restrict__ emb,    // (N, C, C)
    const float* __restrict__ wpool,  // (K, N, C, H)
    const float* __restrict__ bias,   // (N, H)
    float* __restrict__ out)          // (B, N, H)
{
    __shared__ __align__(16) ushort sbuf[4][64 * STR];  // per-wave: E' rows, then M1^T
    __shared__ float inv_lds[4][64];

    const int t = threadIdx.x;
    const int wv = t >> 6;
    const int l = t & 63;
    const int r = l & 15;
    const int g = l >> 4;
    const int n = blockIdx.x * 4 + wv;

    ushort* st   = sbuf[wv];
    float*  invp = inv_lds[wv];

    // ---------- Phase A: lane l computes exp(relu(E[n][l][:])), lane-local sum ----------
    {
        const float* ep = emb + (size_t)n * (C_ * C_) + l * C_;
        float sum = 0.f;
        #pragma unroll
        for (int c4 = 0; c4 < 4; ++c4) {
            float4 p0 = *(const float4*)(ep + c4 * 16 + 0);
            float4 p1 = *(const float4*)(ep + c4 * 16 + 4);
            float4 p2 = *(const float4*)(ep + c4 * 16 + 8);
            float4 p3 = *(const float4*)(ep + c4 * 16 + 12);
            float v[16] = {p0.x, p0.y, p0.z, p0.w, p1.x, p1.y, p1.z, p1.w,
                           p2.x, p2.y, p2.z, p2.w, p3.x, p3.y, p3.z, p3.w};
            bf16x8 e0, e1;
            #pragma unroll
            for (int i = 0; i < 8; ++i) {
                float a = __expf(fmaxf(v[i], 0.f));
                float b = __expf(fmaxf(v[8 + i], 0.f));
                sum += a + b;
                e0[i] = (__bf16)a;
                e1[i] = (__bf16)b;
            }
            *(bf16x8*)(st + l * STR + c4 * 16 + 0) = e0;
            *(bf16x8*)(st + l * STR + c4 * 16 + 8) = e1;
        }
        invp[l] = 1.0f / sum;
    }

    wave_lds_fence();   // E' rows + inv visible to all lanes of this wave

    // ---------- Phase B: M1 = diag(inv) * (E' @ W1) ----------
    // A-frags: rows c of E' (st is row-major E'[c][m])
    bf16x8 af[4][2];
    #pragma unroll
    for (int rt = 0; rt < 4; ++rt)
        #pragma unroll
        for (int kt = 0; kt < 2; ++kt)
            af[rt][kt] = *(const bf16x8*)(st + (rt * 16 + r) * STR + kt * 32 + g * 8);

    float4 invc[4];
    #pragma unroll
    for (int rt = 0; rt < 4; ++rt)
        invc[rt] = *(const float4*)(invp + rt * 16 + g * 4);

    const float* w1 = wpool + ((size_t)N_ + n) * (C_ * H_);
    float wlA[2][8], wlB[2][8];
    #pragma unroll
    for (int kt = 0; kt < 2; ++kt)
        #pragma unroll
        for (int i = 0; i < 8; ++i)
            wlA[kt][i] = w1[(kt * 32 + g * 8 + i) * H_ + r];   // ct = 0

    wave_lds_fence();   // af/invc landed in regs; st may now be overwritten by M1^T

    m_step<0, true >(w1, st, af, invc, wlA, wlB, r, g);
    m_step<1, true >(w1, st, af, invc, wlB, wlA, r, g);
    m_step<2, true >(w1, st, af, invc, wlA, wlB, r, g);
    m_step<3, false>(w1, st, af, invc, wlB, wlA, r, g);

    // ---------- Phase C: OUT = X@W0 + X@M1 + bias ----------
    // Issue X / W0(ct=0) / bias global loads BEFORE the LDS fence (vmcnt-independent).
    bf16x8 xa[2][2];
    #pragma unroll
    for (int mt = 0; mt < 2; ++mt)
        #pragma unroll
        for (int kt = 0; kt < 2; ++kt) {
            const float* xp = x + (size_t)(mt * 16 + r) * (N_ * C_)
                                + (size_t)n * C_ + kt * 32 + g * 8;
            float4 q0 = *(const float4*)xp;
            float4 q1 = *(const float4*)(xp + 4);
            bf16x8 f;
            f[0] = (__bf16)q0.x; f[1] = (__bf16)q0.y;
            f[2] = (__bf16)q0.z; f[3] = (__bf16)q0.w;
            f[4] = (__bf16)q1.x; f[5] = (__bf16)q1.y;
            f[6] = (__bf16)q1.z; f[7] = (__bf16)q1.w;
            xa[mt][kt] = f;
        }

    const float* w0 = wpool + (size_t)n * (C_ * H_);
    float w0A[2][8], w0B[2][8];
    #pragma unroll
    for (int kt = 0; kt < 2; ++kt)
        #pragma unroll
        for (int i = 0; i < 8; ++i)
            w0A[kt][i] = w0[(kt * 32 + g * 8 + i) * H_ + r];   // ct = 0

    float bv[4];
    #pragma unroll
    for (int ct = 0; ct < 4; ++ct)
        bv[ct] = bias[(size_t)n * H_ + ct * 16 + r];

    wave_lds_fence();   // M1^T writes visible

    float* outp = out + (size_t)n * H_ + r;
    c_step<0, true >(w0, st, xa, bv[0], w0A, w0B, outp, r, g);
    c_step<1, true >(w0, st, xa, bv[1], w0B, w0A, outp, r, g);
    c_step<2, true >(w0, st, xa, bv[2], w0A, w0B, outp, r, g);
    c_step<3, false>(w0, st, xa, bv[3], w0B, w0A, outp, r, g);
}

extern "C" void kernel_launch(void* const* d_in, const int* in_sizes, int n_in,
                              void* d_out, int out_size, void* d_ws, size_t ws_size,
                              hipStream_t stream) {
    const float* x    = (const float*)d_in[0];
    const float* emb  = (const float*)d_in[1];
    const float* wp   = (const float*)d_in[2];
    const float* bias = (const float*)d_in[3];
    float* out = (float*)d_out;
    avwgcn_kernel<<<N_ / 4, 256, 0, stream>>>(x, emb, wp, bias, out);
}

// Round 4
// 142.636 us; speedup vs baseline: 1.0554x; 1.0371x over previous
//
#include <hip/hip_runtime.h>
#include <hip/hip_bf16.h>
#include <stdint.h>

// AVWGCN: N=10000 nodes, C=HID=64, B=32, K=2.
// Round 4: strip-pipelined design. 2000 blocks x 5 nodes, 2 blocks/CU.
//  - W0/W1 staged to LDS via global_load_lds (16B, sequential 1KB/inst bursts),
//    double-buffered, issued ONE FULL node-iteration ahead.
//  - E/x/bias prefetched to registers one iteration ahead.
//  - Raw s_barrier + explicit lgkmcnt; single counted vmcnt(21) per iteration
//    (never vmcnt(0) in the steady loop) so prefetches stay in flight across
//    barriers (8-phase-template discipline, m201).
//  - Compute phases identical to round-1 (verified): softmax -> st(bf16 LDS),
//    XG1 = X@S -> g1(bf16 LDS), OUT = X@W0 + XG1@W1 + bias.

constexpr int N_ = 10000;
constexpr int C_ = 64;
constexpr int H_ = 64;
constexpr int STRIP = 5;
constexpr int GRID = N_ / STRIP;   // 2000
constexpr int STB = 72;            // ushort stride: rows 144 B (16B-aligned)

static_assert(N_ % STRIP == 0, "strip must divide N");

typedef __bf16 bf16x8 __attribute__((ext_vector_type(8)));
typedef float  f32x4  __attribute__((ext_vector_type(4)));

static __device__ __forceinline__ unsigned short f2bu(float v) {
    __bf16 b = (__bf16)v;
    return __builtin_bit_cast(unsigned short, b);
}

__global__ __launch_bounds__(256, 2) void avwgcn_kernel(
    const float* __restrict__ x,      // (B, N, C)
    const float* __restrict__ emb,    // (N, C, C)
    const float* __restrict__ wpool,  // (K, N, C, H)
    const float* __restrict__ bias,   // (N, H)
    float* __restrict__ out)          // (B, N, H)
{
    __shared__ float          wlds[2][2][C_ * H_];   // [buf][mat][4096] = 64 KB
    __shared__ unsigned short stb[C_ * STB];         // S^T bf16: st[m][c]   9216 B
    __shared__ unsigned short g1b[32 * STB];         // XG1 bf16: g1[b][m]   4608 B

    const int t = threadIdx.x;
    const int w = t >> 6, l = t & 63, r = l & 15, g = l >> 4;
    const int c = t >> 2, q = t & 3;
    const int n0 = blockIdx.x * STRIP;

    float4 ef[4];    // E row segment (single-buffered: consumed before refill)
    float4 xf[8];    // x frag words  (single-buffered)
    float  bvv[2];   // bias (consumed in phase C, after refill -> double)

    // Issue the full input bundle for node n (21 VMEM insts per wave):
    //   E: 4x dwordx4, x: 8x dwordx4, bias: 1x dword, W0/W1: 8x global_load_lds.
    auto issue = [&](int n, int buf, float& bslot) {
        const float* ep = emb + (size_t)n * (C_ * C_) + t * 16;
        #pragma unroll
        for (int i = 0; i < 4; ++i) ef[i] = *(const float4*)(ep + i * 4);
        #pragma unroll
        for (int mt = 0; mt < 2; ++mt)
            #pragma unroll
            for (int kt = 0; kt < 2; ++kt) {
                const float* xp = x + (size_t)(mt * 16 + r) * (N_ * C_)
                                    + (size_t)n * C_ + kt * 32 + g * 8;
                xf[mt * 4 + kt * 2 + 0] = *(const float4*)xp;
                xf[mt * 4 + kt * 2 + 1] = *(const float4*)(xp + 4);
            }
        bslot = bias[(size_t)n * H_ + w * 16 + r];
        const float* w0g = wpool + (size_t)n * (C_ * H_);
        const float* w1g = w0g + (size_t)N_ * (C_ * H_);
        #pragma unroll
        for (int j = 0; j < 4; ++j) {
            const int ch = w * 4 + j;                 // 1-KB chunk id, 0..15
            __builtin_amdgcn_global_load_lds(
                (const __attribute__((address_space(1))) void*)(w0g + ch * 256 + l * 4),
                (__attribute__((address_space(3))) void*)(&wlds[buf][0][ch * 256]),
                16, 0, 0);
        }
        #pragma unroll
        for (int j = 0; j < 4; ++j) {
            const int ch = w * 4 + j;
            __builtin_amdgcn_global_load_lds(
                (const __attribute__((address_space(1))) void*)(w1g + ch * 256 + l * 4),
                (__attribute__((address_space(3))) void*)(&wlds[buf][1][ch * 256]),
                16, 0, 0);
        }
    };

    issue(n0, 0, bvv[0]);   // prologue: bundle(0)

    #pragma unroll
    for (int it = 0; it < STRIP; ++it) {
        const int p = it & 1;
        const int n = n0 + it;

        // ---------- Phase A: softmax(relu(E[n])) from regs -> stb ----------
        {
            float v[16];
            #pragma unroll
            for (int i = 0; i < 4; ++i) {
                v[i*4+0] = ef[i].x; v[i*4+1] = ef[i].y;
                v[i*4+2] = ef[i].z; v[i*4+3] = ef[i].w;
            }
            float s = 0.f;
            #pragma unroll
            for (int i = 0; i < 16; ++i) {
                float e = __expf(fmaxf(v[i], 0.f));
                v[i] = e; s += e;
            }
            s += __shfl_xor(s, 1);
            s += __shfl_xor(s, 2);
            const float inv = 1.0f / s;
            #pragma unroll
            for (int i = 0; i < 16; ++i)
                stb[(q * 16 + i) * STB + c] = f2bu(v[i] * inv);  // transposed
        }
        // X A-frags from prefetched regs
        bf16x8 xa[2][2];
        #pragma unroll
        for (int mt = 0; mt < 2; ++mt)
            #pragma unroll
            for (int kt = 0; kt < 2; ++kt) {
                float4 a0 = xf[mt * 4 + kt * 2 + 0];
                float4 a1 = xf[mt * 4 + kt * 2 + 1];
                bf16x8 f;
                f[0] = (__bf16)a0.x; f[1] = (__bf16)a0.y;
                f[2] = (__bf16)a0.z; f[3] = (__bf16)a0.w;
                f[4] = (__bf16)a1.x; f[5] = (__bf16)a1.y;
                f[6] = (__bf16)a1.z; f[7] = (__bf16)a1.w;
                xa[mt][kt] = f;
            }

        // ---- bar1: stb visible; prior phase-C LDS reads drained wave-locally ----
        __builtin_amdgcn_sched_barrier(0);
        asm volatile("s_waitcnt lgkmcnt(0)" ::: "memory");
        __builtin_amdgcn_s_barrier();
        __builtin_amdgcn_sched_barrier(0);

        // Prefetch bundle for node n+1 (into the buffer freed by C(it-1))
        if (it + 1 < STRIP) issue(n0 + it + 1, p ^ 1, bvv[p ^ 1]);

        // ---------- Phase B: XG1 = X @ S ----------
        f32x4 accg[2];
        accg[0] = (f32x4){0.f, 0.f, 0.f, 0.f};
        accg[1] = (f32x4){0.f, 0.f, 0.f, 0.f};
        #pragma unroll
        for (int kt = 0; kt < 2; ++kt) {
            bf16x8 sb = *(const bf16x8*)(stb + (w * 16 + r) * STB + kt * 32 + g * 8);
            #pragma unroll
            for (int mt = 0; mt < 2; ++mt)
                accg[mt] = __builtin_amdgcn_mfma_f32_16x16x32_bf16(
                    xa[mt][kt], sb, accg[mt], 0, 0, 0);
        }
        #pragma unroll
        for (int mt = 0; mt < 2; ++mt)
            #pragma unroll
            for (int ri = 0; ri < 4; ++ri)
                g1b[(mt * 16 + g * 4 + ri) * STB + (w * 16 + r)] = f2bu(accg[mt][ri]);

        // ---- bar2: g1b visible AND W(it) landed in LDS. Counted vmcnt keeps
        //      the 21 bundle(it+1) prefetches in flight; drains everything older.
        __builtin_amdgcn_sched_barrier(0);
        if (it + 1 < STRIP)
            asm volatile("s_waitcnt vmcnt(21) lgkmcnt(0)" ::: "memory");
        else
            asm volatile("s_waitcnt vmcnt(0) lgkmcnt(0)" ::: "memory");
        __builtin_amdgcn_s_barrier();
        __builtin_amdgcn_sched_barrier(0);

        // ---------- Phase C: OUT = X@W0 + XG1@W1 + bias ----------
        bf16x8 ga[2][2];
        #pragma unroll
        for (int mt = 0; mt < 2; ++mt)
            #pragma unroll
            for (int kt = 0; kt < 2; ++kt)
                ga[mt][kt] = *(const bf16x8*)(g1b + (mt * 16 + r) * STB + kt * 32 + g * 8);

        const float bv = bvv[p];
        f32x4 acc[2];
        acc[0] = (f32x4){bv, bv, bv, bv};
        acc[1] = (f32x4){bv, bv, bv, bv};

        const float* w0l = &wlds[p][0][0];
        const float* w1l = &wlds[p][1][0];
        #pragma unroll
        for (int kt = 0; kt < 2; ++kt) {
            bf16x8 wb0, wb1;
            #pragma unroll
            for (int i = 0; i < 8; ++i) {
                const int idx = (kt * 32 + g * 8 + i) * H_ + w * 16 + r;
                wb0[i] = (__bf16)w0l[idx];
                wb1[i] = (__bf16)w1l[idx];
            }
            #pragma unroll
            for (int mt = 0; mt < 2; ++mt) {
                acc[mt] = __builtin_amdgcn_mfma_f32_16x16x32_bf16(
                    xa[mt][kt], wb0, acc[mt], 0, 0, 0);
                acc[mt] = __builtin_amdgcn_mfma_f32_16x16x32_bf16(
                    ga[mt][kt], wb1, acc[mt], 0, 0, 0);
            }
        }

        #pragma unroll
        for (int mt = 0; mt < 2; ++mt)
            #pragma unroll
            for (int ri = 0; ri < 4; ++ri) {
                const int b = mt * 16 + g * 4 + ri;
                const int o = w * 16 + r;
                out[(size_t)b * (N_ * H_) + (size_t)n * H_ + o] = acc[mt][ri];
            }
    }
}

extern "C" void kernel_launch(void* const* d_in, const int* in_sizes, int n_in,
                              void* d_out, int out_size, void* d_ws, size_t ws_size,
                              hipStream_t stream) {
    const float* x    = (const float*)d_in[0];
    const float* emb  = (const float*)d_in[1];
    const float* wp   = (const float*)d_in[2];
    const float* bias = (const float*)d_in[3];
    float* out = (float*)d_out;
    avwgcn_kernel<<<GRID, 256, 0, stream>>>(x, emb, wp, bias, out);
}